// Round 2
// baseline (3072.235 us; speedup 1.0000x reference)
//
#include <hip/hip_runtime.h>
#include <cstdint>

#define D 128
#define RPW 6        // rows per wave per sweep (transform)
#define TWAVES 4     // waves per transform block
#define TBLOCKS 256  // transform grid

// ---------------- scatter: msg[col] += x[row], cnt[col] += 1 ----------------
// 32 lanes per edge; each lane handles one float4 of the 128-dim feature.
__global__ __launch_bounds__(256) void sage_scatter(
    const float* __restrict__ x,
    const int* __restrict__ ei,   // [2][E]: row = ei[e], col = ei[E+e]
    float* msg, float* cnt, int E)
{
    int t = blockIdx.x * 256 + threadIdx.x;
    int e = t >> 5;
    if (e >= E) return;
    int l = t & 31;
    int row = ei[e];
    int col = ei[E + e];
    float4 v = reinterpret_cast<const float4*>(x)[(size_t)row * 32 + l];
    float* dst = msg + (size_t)col * D + l * 4;
    unsafeAtomicAdd(dst + 0, v.x);
    unsafeAtomicAdd(dst + 1, v.y);
    unsafeAtomicAdd(dst + 2, v.z);
    unsafeAtomicAdd(dst + 3, v.w);
    if (l == 0) unsafeAtomicAdd(cnt + col, 1.0f);
}

// ---------------- transform: out = normalize(mean@Wrel^T + b + x@Wroot^T) ---
// W matrices staged transposed in LDS as float2 pairs with XOR swizzle:
//   element (j,k) lives at wlds[mat][k*64 + ((j>>1)^(k&31))], sub j&1.
// Read at iter k by lane l: slot = l^(k&31) -> recovers pair p=l. Conflict-free.
// Each wave owns RPW rows per sweep; next sweep's rows are prefetched into
// registers during compute to hide global latency at 1 block/CU occupancy.
// In-place: msg rows are read (into LDS) before the same rows are written.
__global__ __launch_bounds__(256) void sage_transform(
    float* inout,                 // msg in -> normalized out (row-wise in-place)
    const float* __restrict__ xg,
    const float* __restrict__ cnt,
    const float* __restrict__ Wrel,
    const float* __restrict__ brel,
    const float* __restrict__ Wroot,
    int N, int stride)            // stride = TBLOCKS*TWAVES*RPW
{
    __shared__ float2 wlds[2][D * 64];            // 128 KiB
    __shared__ float rowbuf[TWAVES][RPW][2][D];   // 24 KiB

    const int tid = threadIdx.x;
    const int wave = tid >> 6;
    const int lane = tid & 63;

    // stage both W matrices, transposed + swizzled
    for (int idx = tid; idx < D * D; idx += 256) {
        int j = idx >> 7;
        int k = idx & 127;
        int slot = (j >> 1) ^ (k & 31);
        int sub = j & 1;
        reinterpret_cast<float*>(&wlds[0][k * 64 + slot])[sub] = Wrel[idx];
        reinterpret_cast<float*>(&wlds[1][k * 64 + slot])[sub] = Wroot[idx];
    }
    float2 bias = reinterpret_cast<const float2*>(brel)[lane];
    __syncthreads();

    const int gw = blockIdx.x * TWAVES + wave;
    int base = gw * RPW;

    float2 pm[RPW], px[RPW];
    float pc[RPW];

    #pragma unroll
    for (int r = 0; r < RPW; ++r) {
        int row = base + r;
        if (row < N) {
            pm[r] = reinterpret_cast<const float2*>(inout)[(size_t)row * 64 + lane];
            px[r] = reinterpret_cast<const float2*>(xg)[(size_t)row * 64 + lane];
            pc[r] = cnt[row];
        }
    }

    while (base < N) {
        // stage current row batch into LDS (mean scaled by 1/max(cnt,1))
        #pragma unroll
        for (int r = 0; r < RPW; ++r) {
            int row = base + r;
            if (row < N) {
                float rc = 1.0f / fmaxf(pc[r], 1.0f);
                float2 m = pm[r];
                m.x *= rc; m.y *= rc;
                *reinterpret_cast<float2*>(&rowbuf[wave][r][0][lane * 2]) = m;
                *reinterpret_cast<float2*>(&rowbuf[wave][r][1][lane * 2]) = px[r];
            }
        }
        int nbase = base + stride;
        // prefetch next sweep (overlaps with compute below)
        if (nbase < N) {
            #pragma unroll
            for (int r = 0; r < RPW; ++r) {
                int row = nbase + r;
                if (row < N) {
                    pm[r] = reinterpret_cast<const float2*>(inout)[(size_t)row * 64 + lane];
                    px[r] = reinterpret_cast<const float2*>(xg)[(size_t)row * 64 + lane];
                    pc[r] = cnt[row];
                }
            }
        }

        float2 acc[RPW];
        #pragma unroll
        for (int r = 0; r < RPW; ++r) acc[r] = make_float2(0.f, 0.f);

        #pragma unroll 4
        for (int k = 0; k < D; ++k) {
            int slot = lane ^ (k & 31);
            float2 wr = wlds[0][k * 64 + slot];
            float2 wo = wlds[1][k * 64 + slot];
            #pragma unroll
            for (int r = 0; r < RPW; ++r) {
                float m = rowbuf[wave][r][0][k];
                float xx = rowbuf[wave][r][1][k];
                acc[r].x = fmaf(m, wr.x, acc[r].x);
                acc[r].y = fmaf(m, wr.y, acc[r].y);
                acc[r].x = fmaf(xx, wo.x, acc[r].x);
                acc[r].y = fmaf(xx, wo.y, acc[r].y);
            }
        }

        // bias + row L2 norm + in-place store
        #pragma unroll
        for (int r = 0; r < RPW; ++r) {
            int row = base + r;
            if (row < N) {
                float2 a = acc[r];
                a.x += bias.x; a.y += bias.y;
                float ss = fmaf(a.x, a.x, a.y * a.y);
                #pragma unroll
                for (int off = 32; off > 0; off >>= 1)
                    ss += __shfl_xor(ss, off, 64);
                float inv = 1.0f / fmaxf(sqrtf(ss), 1e-12f);
                reinterpret_cast<float2*>(inout)[(size_t)row * 64 + lane] =
                    make_float2(a.x * inv, a.y * inv);
            }
        }
        base = nbase;
    }
}

extern "C" void kernel_launch(void* const* d_in, const int* in_sizes, int n_in,
                              void* d_out, int out_size, void* d_ws, size_t ws_size,
                              hipStream_t stream)
{
    const float* x    = (const float*)d_in[0];
    // d_in[1] = res_size (== N for this problem; derived from in_sizes instead)
    const int*   ei   = (const int*)d_in[2];
    const float* Wrel = (const float*)d_in[3];
    const float* brel = (const float*)d_in[4];
    const float* Wroot= (const float*)d_in[5];
    int N = in_sizes[0] / D;
    int E = in_sizes[2] / 2;
    float* out = (float*)d_out;
    float* cnt = (float*)d_ws;   // N floats

    hipMemsetAsync(out, 0, (size_t)N * D * sizeof(float), stream);
    hipMemsetAsync(cnt, 0, (size_t)N * sizeof(float), stream);

    long long totalT = (long long)E * 32;
    int sblocks = (int)((totalT + 255) / 256);
    sage_scatter<<<sblocks, 256, 0, stream>>>(x, ei, out, cnt, E);

    int stride = TBLOCKS * TWAVES * RPW;
    sage_transform<<<TBLOCKS, 256, 0, stream>>>(out, x, cnt, Wrel, brel, Wroot, N, stride);
}

// Round 3
// 845.633 us; speedup vs baseline: 3.6331x; 3.6331x over previous
//
#include <hip/hip_runtime.h>
#include <cstdint>

#define D 128
#define RPW 6        // rows per wave per sweep (transform)
#define TWAVES 4     // waves per transform block
#define TBLOCKS 256  // transform grid

// ---------------- CSR build: hist -> scan -> fill ---------------------------
__global__ __launch_bounds__(256) void sage_hist(
    const int* __restrict__ ei, int* hist, int E)
{
    int e = blockIdx.x * 256 + threadIdx.x;
    if (e < E) atomicAdd(&hist[ei[E + e]], 1);
}

// single-block scan over N counters -> row_ptr (exclusive) + cursor copy
__global__ __launch_bounds__(1024) void sage_scan(
    const int* __restrict__ hist, int* row_ptr, int* cursor, int N)
{
    __shared__ int s[1024];
    int t = threadIdx.x;
    int chunk = (N + 1023) / 1024;
    int lo = t * chunk, hi = min(lo + chunk, N);
    int sum = 0;
    for (int i = lo; i < hi; ++i) sum += hist[i];
    s[t] = sum;
    __syncthreads();
    for (int off = 1; off < 1024; off <<= 1) {
        int v = (t >= off) ? s[t - off] : 0;
        __syncthreads();
        s[t] += v;
        __syncthreads();
    }
    int p = s[t] - sum;  // exclusive prefix
    for (int i = lo; i < hi; ++i) {
        row_ptr[i] = p;
        cursor[i] = p;
        p += hist[i];
    }
    if (t == 1023) row_ptr[N] = s[1023];
}

__global__ __launch_bounds__(256) void sage_fill(
    const int* __restrict__ ei, int* cursor, int* perm, int E)
{
    int e = blockIdx.x * 256 + threadIdx.x;
    if (e < E) {
        int c = ei[E + e];
        int p = atomicAdd(&cursor[c], 1);
        perm[p] = ei[e];   // source row of this edge
    }
}

// ---------------- gather: out[i] = mean_{e in N(i)} x[src(e)] ---------------
// one wave per node; 2 edges per iteration (half-wave each, 32 lanes x float4)
__global__ __launch_bounds__(256) void sage_gather(
    const float* __restrict__ x,
    const int* __restrict__ row_ptr,
    const int* __restrict__ perm,
    float* out, int N)
{
    int wave = threadIdx.x >> 6;
    int lane = threadIdx.x & 63;
    int node = blockIdx.x * 4 + wave;
    if (node >= N) return;
    int start = row_ptr[node], end = row_ptr[node + 1];
    int half = lane >> 5, hl = lane & 31;
    float4 acc = make_float4(0.f, 0.f, 0.f, 0.f);
    for (int e = start + half; e < end; e += 2) {
        int r = perm[e];
        float4 v = reinterpret_cast<const float4*>(x)[(size_t)r * 32 + hl];
        acc.x += v.x; acc.y += v.y; acc.z += v.z; acc.w += v.w;
    }
    acc.x += __shfl_xor(acc.x, 32, 64);
    acc.y += __shfl_xor(acc.y, 32, 64);
    acc.z += __shfl_xor(acc.z, 32, 64);
    acc.w += __shfl_xor(acc.w, 32, 64);
    float sc = 1.0f / fmaxf((float)(end - start), 1.0f);
    if (half == 0) {
        reinterpret_cast<float4*>(out)[(size_t)node * 32 + hl] =
            make_float4(acc.x * sc, acc.y * sc, acc.z * sc, acc.w * sc);
    }
}

// ---------------- transform: out = normalize(mean@Wrel^T + b + x@Wroot^T) ---
// W matrices staged transposed in LDS as float2 pairs with XOR swizzle:
//   element (j,k) lives at wlds[mat][k*64 + ((j>>1)^(k&31))], sub j&1.
// Read at iter k by lane l: slot = l^(k&31) -> recovers pair p=l. Conflict-free.
__global__ __launch_bounds__(256) void sage_transform(
    float* inout,                 // mean in -> normalized out (row-wise in-place)
    const float* __restrict__ xg,
    const float* __restrict__ Wrel,
    const float* __restrict__ brel,
    const float* __restrict__ Wroot,
    int N, int stride)            // stride = TBLOCKS*TWAVES*RPW
{
    __shared__ float2 wlds[2][D * 64];            // 128 KiB
    __shared__ float rowbuf[TWAVES][RPW][2][D];   // 24 KiB

    const int tid = threadIdx.x;
    const int wave = tid >> 6;
    const int lane = tid & 63;

    for (int idx = tid; idx < D * D; idx += 256) {
        int j = idx >> 7;
        int k = idx & 127;
        int slot = (j >> 1) ^ (k & 31);
        int sub = j & 1;
        reinterpret_cast<float*>(&wlds[0][k * 64 + slot])[sub] = Wrel[idx];
        reinterpret_cast<float*>(&wlds[1][k * 64 + slot])[sub] = Wroot[idx];
    }
    float2 bias = reinterpret_cast<const float2*>(brel)[lane];
    __syncthreads();

    const int gw = blockIdx.x * TWAVES + wave;
    int base = gw * RPW;

    float2 pm[RPW], px[RPW];

    #pragma unroll
    for (int r = 0; r < RPW; ++r) {
        int row = base + r;
        if (row < N) {
            pm[r] = reinterpret_cast<const float2*>(inout)[(size_t)row * 64 + lane];
            px[r] = reinterpret_cast<const float2*>(xg)[(size_t)row * 64 + lane];
        }
    }

    while (base < N) {
        #pragma unroll
        for (int r = 0; r < RPW; ++r) {
            int row = base + r;
            if (row < N) {
                *reinterpret_cast<float2*>(&rowbuf[wave][r][0][lane * 2]) = pm[r];
                *reinterpret_cast<float2*>(&rowbuf[wave][r][1][lane * 2]) = px[r];
            }
        }
        int nbase = base + stride;
        if (nbase < N) {
            #pragma unroll
            for (int r = 0; r < RPW; ++r) {
                int row = nbase + r;
                if (row < N) {
                    pm[r] = reinterpret_cast<const float2*>(inout)[(size_t)row * 64 + lane];
                    px[r] = reinterpret_cast<const float2*>(xg)[(size_t)row * 64 + lane];
                }
            }
        }

        float2 acc[RPW];
        #pragma unroll
        for (int r = 0; r < RPW; ++r) acc[r] = make_float2(0.f, 0.f);

        #pragma unroll 4
        for (int k = 0; k < D; ++k) {
            int slot = lane ^ (k & 31);
            float2 wr = wlds[0][k * 64 + slot];
            float2 wo = wlds[1][k * 64 + slot];
            #pragma unroll
            for (int r = 0; r < RPW; ++r) {
                float m = rowbuf[wave][r][0][k];
                float xx = rowbuf[wave][r][1][k];
                acc[r].x = fmaf(m, wr.x, acc[r].x);
                acc[r].y = fmaf(m, wr.y, acc[r].y);
                acc[r].x = fmaf(xx, wo.x, acc[r].x);
                acc[r].y = fmaf(xx, wo.y, acc[r].y);
            }
        }

        #pragma unroll
        for (int r = 0; r < RPW; ++r) {
            int row = base + r;
            if (row < N) {
                float2 a = acc[r];
                a.x += bias.x; a.y += bias.y;
                float ss = fmaf(a.x, a.x, a.y * a.y);
                #pragma unroll
                for (int off = 32; off > 0; off >>= 1)
                    ss += __shfl_xor(ss, off, 64);
                float inv = 1.0f / fmaxf(sqrtf(ss), 1e-12f);
                reinterpret_cast<float2*>(inout)[(size_t)row * 64 + lane] =
                    make_float2(a.x * inv, a.y * inv);
            }
        }
        base = nbase;
    }
}

extern "C" void kernel_launch(void* const* d_in, const int* in_sizes, int n_in,
                              void* d_out, int out_size, void* d_ws, size_t ws_size,
                              hipStream_t stream)
{
    const float* x    = (const float*)d_in[0];
    const int*   ei   = (const int*)d_in[2];
    const float* Wrel = (const float*)d_in[3];
    const float* brel = (const float*)d_in[4];
    const float* Wroot= (const float*)d_in[5];
    int N = in_sizes[0] / D;
    int E = in_sizes[2] / 2;
    float* out = (float*)d_out;

    // workspace layout (ints): hist[N] | row_ptr[N+1] | cursor[N] | perm[E]
    int* hist    = (int*)d_ws;
    int* row_ptr = hist + N;
    int* cursor  = row_ptr + N + 1;
    int* perm    = cursor + N;

    hipMemsetAsync(hist, 0, (size_t)N * sizeof(int), stream);

    int eblocks = (E + 255) / 256;
    sage_hist<<<eblocks, 256, 0, stream>>>(ei, hist, E);
    sage_scan<<<1, 1024, 0, stream>>>(hist, row_ptr, cursor, N);
    sage_fill<<<eblocks, 256, 0, stream>>>(ei, cursor, perm, E);
    sage_gather<<<(N + 3) / 4, 256, 0, stream>>>(x, row_ptr, perm, out, N);

    int stride = TBLOCKS * TWAVES * RPW;
    sage_transform<<<TBLOCKS, 256, 0, stream>>>(out, x, Wrel, brel, Wroot, N, stride);
}

// Round 4
// 630.768 us; speedup vs baseline: 4.8706x; 1.3406x over previous
//
#include <hip/hip_runtime.h>
#include <cstdint>

#define D 128
#define RPW 6        // rows per wave per sweep (transform)
#define TWAVES 4     // waves per transform block
#define TBLOCKS 256  // transform grid
#define STILE 1024   // scan tile (256 threads x int4)

// ---------------- CSR build: hist -> hierarchical scan -> fill --------------
__global__ __launch_bounds__(256) void sage_hist(
    const int* __restrict__ ei, int* hist, int E)
{
    int e = blockIdx.x * 256 + threadIdx.x;
    if (e < E) atomicAdd(&hist[ei[E + e]], 1);
}

// pass A: per-tile sums
__global__ __launch_bounds__(256) void scan_partial(
    const int* __restrict__ hist, int* bsum, int N)
{
    int t = threadIdx.x;
    int idx = blockIdx.x * STILE + t * 4;
    int4 v = make_int4(0, 0, 0, 0);
    if (idx + 3 < N) v = *reinterpret_cast<const int4*>(hist + idx);
    else {
        if (idx + 0 < N) v.x = hist[idx + 0];
        if (idx + 1 < N) v.y = hist[idx + 1];
        if (idx + 2 < N) v.z = hist[idx + 2];
        if (idx + 3 < N) v.w = hist[idx + 3];
    }
    int s = v.x + v.y + v.z + v.w;
    #pragma unroll
    for (int off = 1; off < 64; off <<= 1) s += __shfl_xor(s, off, 64);
    __shared__ int ws[4];
    if ((t & 63) == 0) ws[t >> 6] = s;
    __syncthreads();
    if (t == 0) bsum[blockIdx.x] = ws[0] + ws[1] + ws[2] + ws[3];
}

// pass B: exclusive scan of tile sums (nb <= 1024)
__global__ __launch_bounds__(1024) void scan_bsums(
    const int* __restrict__ bsum, int* boff, int nb)
{
    __shared__ int s[1024];
    int t = threadIdx.x;
    int v = (t < nb) ? bsum[t] : 0;
    s[t] = v;
    __syncthreads();
    for (int off = 1; off < 1024; off <<= 1) {
        int u = (t >= off) ? s[t - off] : 0;
        __syncthreads();
        s[t] += u;
        __syncthreads();
    }
    if (t < nb) boff[t] = s[t] - v;
}

// pass C: local prefix + tile offset -> row_ptr, cursor
__global__ __launch_bounds__(256) void scan_final(
    const int* __restrict__ hist, const int* __restrict__ boff,
    int* row_ptr, int* cursor, int N, int E)
{
    int t = threadIdx.x;
    int idx = blockIdx.x * STILE + t * 4;
    int4 v = make_int4(0, 0, 0, 0);
    if (idx + 3 < N) v = *reinterpret_cast<const int4*>(hist + idx);
    else {
        if (idx + 0 < N) v.x = hist[idx + 0];
        if (idx + 1 < N) v.y = hist[idx + 1];
        if (idx + 2 < N) v.z = hist[idx + 2];
        if (idx + 3 < N) v.w = hist[idx + 3];
    }
    int tsum = v.x + v.y + v.z + v.w;
    int lane = t & 63, wv = t >> 6;
    int incl = tsum;
    #pragma unroll
    for (int off = 1; off < 64; off <<= 1) {
        int u = __shfl_up(incl, off, 64);
        if (lane >= off) incl += u;
    }
    __shared__ int wsum[4];
    if (lane == 63) wsum[wv] = incl;
    __syncthreads();
    int woff = 0;
    for (int w = 0; w < wv; ++w) woff += wsum[w];
    int excl = woff + (incl - tsum) + boff[blockIdx.x];
    int4 rp;
    rp.x = excl;
    rp.y = excl + v.x;
    rp.z = rp.y + v.y;
    rp.w = rp.z + v.z;
    if (idx + 3 < N) {
        *reinterpret_cast<int4*>(row_ptr + idx) = rp;
        *reinterpret_cast<int4*>(cursor + idx) = rp;
    } else {
        if (idx + 0 < N) { row_ptr[idx + 0] = rp.x; cursor[idx + 0] = rp.x; }
        if (idx + 1 < N) { row_ptr[idx + 1] = rp.y; cursor[idx + 1] = rp.y; }
        if (idx + 2 < N) { row_ptr[idx + 2] = rp.z; cursor[idx + 2] = rp.z; }
        if (idx + 3 < N) { row_ptr[idx + 3] = rp.w; cursor[idx + 3] = rp.w; }
    }
    if (blockIdx.x == 0 && t == 0) row_ptr[N] = E;
}

__global__ __launch_bounds__(256) void sage_fill(
    const int* __restrict__ ei, int* cursor, int* perm, int E)
{
    int e = blockIdx.x * 256 + threadIdx.x;
    if (e < E) {
        int c = ei[E + e];
        int p = atomicAdd(&cursor[c], 1);
        perm[p] = ei[e];   // source row of this edge
    }
}

// ---------------- gather: out[i] = mean_{e in N(i)} x[src(e)] ---------------
// one wave per node; 2 edges per iteration (half-wave each, 32 lanes x float4)
__global__ __launch_bounds__(256) void sage_gather(
    const float* __restrict__ x,
    const int* __restrict__ row_ptr,
    const int* __restrict__ perm,
    float* out, int N)
{
    int wave = threadIdx.x >> 6;
    int lane = threadIdx.x & 63;
    int node = blockIdx.x * 4 + wave;
    if (node >= N) return;
    int start = row_ptr[node], end = row_ptr[node + 1];
    int half = lane >> 5, hl = lane & 31;
    float4 acc = make_float4(0.f, 0.f, 0.f, 0.f);
    for (int e = start + half; e < end; e += 2) {
        int r = perm[e];
        float4 v = reinterpret_cast<const float4*>(x)[(size_t)r * 32 + hl];
        acc.x += v.x; acc.y += v.y; acc.z += v.z; acc.w += v.w;
    }
    acc.x += __shfl_xor(acc.x, 32, 64);
    acc.y += __shfl_xor(acc.y, 32, 64);
    acc.z += __shfl_xor(acc.z, 32, 64);
    acc.w += __shfl_xor(acc.w, 32, 64);
    float sc = 1.0f / fmaxf((float)(end - start), 1.0f);
    if (half == 0) {
        reinterpret_cast<float4*>(out)[(size_t)node * 32 + hl] =
            make_float4(acc.x * sc, acc.y * sc, acc.z * sc, acc.w * sc);
    }
}

// ---------------- transform: out = normalize(mean@Wrel^T + b + x@Wroot^T) ---
__global__ __launch_bounds__(256) void sage_transform(
    float* inout,                 // mean in -> normalized out (row-wise in-place)
    const float* __restrict__ xg,
    const float* __restrict__ Wrel,
    const float* __restrict__ brel,
    const float* __restrict__ Wroot,
    int N, int stride)            // stride = TBLOCKS*TWAVES*RPW
{
    __shared__ float2 wlds[2][D * 64];            // 128 KiB
    __shared__ float rowbuf[TWAVES][RPW][2][D];   // 24 KiB

    const int tid = threadIdx.x;
    const int wave = tid >> 6;
    const int lane = tid & 63;

    for (int idx = tid; idx < D * D; idx += 256) {
        int j = idx >> 7;
        int k = idx & 127;
        int slot = (j >> 1) ^ (k & 31);
        int sub = j & 1;
        reinterpret_cast<float*>(&wlds[0][k * 64 + slot])[sub] = Wrel[idx];
        reinterpret_cast<float*>(&wlds[1][k * 64 + slot])[sub] = Wroot[idx];
    }
    float2 bias = reinterpret_cast<const float2*>(brel)[lane];
    __syncthreads();

    const int gw = blockIdx.x * TWAVES + wave;
    int base = gw * RPW;

    float2 pm[RPW], px[RPW];

    #pragma unroll
    for (int r = 0; r < RPW; ++r) {
        int row = base + r;
        if (row < N) {
            pm[r] = reinterpret_cast<const float2*>(inout)[(size_t)row * 64 + lane];
            px[r] = reinterpret_cast<const float2*>(xg)[(size_t)row * 64 + lane];
        }
    }

    while (base < N) {
        #pragma unroll
        for (int r = 0; r < RPW; ++r) {
            int row = base + r;
            if (row < N) {
                *reinterpret_cast<float2*>(&rowbuf[wave][r][0][lane * 2]) = pm[r];
                *reinterpret_cast<float2*>(&rowbuf[wave][r][1][lane * 2]) = px[r];
            }
        }
        int nbase = base + stride;
        if (nbase < N) {
            #pragma unroll
            for (int r = 0; r < RPW; ++r) {
                int row = nbase + r;
                if (row < N) {
                    pm[r] = reinterpret_cast<const float2*>(inout)[(size_t)row * 64 + lane];
                    px[r] = reinterpret_cast<const float2*>(xg)[(size_t)row * 64 + lane];
                }
            }
        }

        float2 acc[RPW];
        #pragma unroll
        for (int r = 0; r < RPW; ++r) acc[r] = make_float2(0.f, 0.f);

        #pragma unroll 4
        for (int k = 0; k < D; ++k) {
            int slot = lane ^ (k & 31);
            float2 wr = wlds[0][k * 64 + slot];
            float2 wo = wlds[1][k * 64 + slot];
            #pragma unroll
            for (int r = 0; r < RPW; ++r) {
                float m = rowbuf[wave][r][0][k];
                float xx = rowbuf[wave][r][1][k];
                acc[r].x = fmaf(m, wr.x, acc[r].x);
                acc[r].y = fmaf(m, wr.y, acc[r].y);
                acc[r].x = fmaf(xx, wo.x, acc[r].x);
                acc[r].y = fmaf(xx, wo.y, acc[r].y);
            }
        }

        #pragma unroll
        for (int r = 0; r < RPW; ++r) {
            int row = base + r;
            if (row < N) {
                float2 a = acc[r];
                a.x += bias.x; a.y += bias.y;
                float ss = fmaf(a.x, a.x, a.y * a.y);
                #pragma unroll
                for (int off = 32; off > 0; off >>= 1)
                    ss += __shfl_xor(ss, off, 64);
                float inv = 1.0f / fmaxf(sqrtf(ss), 1e-12f);
                reinterpret_cast<float2*>(inout)[(size_t)row * 64 + lane] =
                    make_float2(a.x * inv, a.y * inv);
            }
        }
        base = nbase;
    }
}

extern "C" void kernel_launch(void* const* d_in, const int* in_sizes, int n_in,
                              void* d_out, int out_size, void* d_ws, size_t ws_size,
                              hipStream_t stream)
{
    const float* x    = (const float*)d_in[0];
    const int*   ei   = (const int*)d_in[2];
    const float* Wrel = (const float*)d_in[3];
    const float* brel = (const float*)d_in[4];
    const float* Wroot= (const float*)d_in[5];
    int N = in_sizes[0] / D;
    int E = in_sizes[2] / 2;
    float* out = (float*)d_out;

    int nb = (N + STILE - 1) / STILE;

    // workspace (ints): hist[N] | row_ptr[N+1] | cursor[N] | bsum[nb] | boff[nb] | perm[E]
    int* hist    = (int*)d_ws;
    int* row_ptr = hist + N;
    int* cursor  = row_ptr + N + 1;
    int* bsum    = cursor + N;
    int* boff    = bsum + nb;
    int* perm    = boff + nb;

    hipMemsetAsync(hist, 0, (size_t)N * sizeof(int), stream);

    int eblocks = (E + 255) / 256;
    sage_hist<<<eblocks, 256, 0, stream>>>(ei, hist, E);
    scan_partial<<<nb, 256, 0, stream>>>(hist, bsum, N);
    scan_bsums<<<1, 1024, 0, stream>>>(bsum, boff, nb);
    scan_final<<<nb, 256, 0, stream>>>(hist, boff, row_ptr, cursor, N, E);
    sage_fill<<<eblocks, 256, 0, stream>>>(ei, cursor, perm, E);
    sage_gather<<<(N + 3) / 4, 256, 0, stream>>>(x, row_ptr, perm, out, N);

    int stride = TBLOCKS * TWAVES * RPW;
    sage_transform<<<TBLOCKS, 256, 0, stream>>>(out, x, Wrel, brel, Wroot, N, stride);
}

// Round 5
// 540.491 us; speedup vs baseline: 5.6842x; 1.1670x over previous
//
#include <hip/hip_runtime.h>
#include <cstdint>

#define D 128
#define STILE 1024   // scan tile (256 threads x int4)

using short8 = __attribute__((ext_vector_type(8))) short;
using f32x4  = __attribute__((ext_vector_type(4))) float;

// fp32 -> bf16 bits, round-to-nearest-even
__device__ inline unsigned short f2bf(float f) {
    unsigned u = __float_as_uint(f);
    return (unsigned short)((u + 0x7FFFu + ((u >> 16) & 1u)) >> 16);
}
__device__ inline float bf2f(unsigned short h) {
    return __uint_as_float(((unsigned)h) << 16);
}

// ---------------- W prep: [Wrel | Wroot] -> bf16 hi/lo, row-major [128][256]
__global__ __launch_bounds__(256) void sage_wprep(
    const float* __restrict__ Wrel, const float* __restrict__ Wroot,
    unsigned short* Whi, unsigned short* Wlo)
{
    int t = blockIdx.x * 256 + threadIdx.x;   // 0..32767
    int j = t >> 8, k = t & 255;
    float f = (k < 128) ? Wrel[j * 128 + k] : Wroot[j * 128 + (k - 128)];
    unsigned short hi = f2bf(f);
    Whi[t] = hi;
    Wlo[t] = f2bf(f - bf2f(hi));
}

// ---------------- CSR build: hist -> hierarchical scan -> fill --------------
__global__ __launch_bounds__(256) void sage_hist(
    const int* __restrict__ ei, int* hist, int E)
{
    int e = blockIdx.x * 256 + threadIdx.x;
    if (e < E) atomicAdd(&hist[ei[E + e]], 1);
}

__global__ __launch_bounds__(256) void scan_partial(
    const int* __restrict__ hist, int* bsum, int N)
{
    int t = threadIdx.x;
    int idx = blockIdx.x * STILE + t * 4;
    int4 v = make_int4(0, 0, 0, 0);
    if (idx + 3 < N) v = *reinterpret_cast<const int4*>(hist + idx);
    else {
        if (idx + 0 < N) v.x = hist[idx + 0];
        if (idx + 1 < N) v.y = hist[idx + 1];
        if (idx + 2 < N) v.z = hist[idx + 2];
        if (idx + 3 < N) v.w = hist[idx + 3];
    }
    int s = v.x + v.y + v.z + v.w;
    #pragma unroll
    for (int off = 1; off < 64; off <<= 1) s += __shfl_xor(s, off, 64);
    __shared__ int ws[4];
    if ((t & 63) == 0) ws[t >> 6] = s;
    __syncthreads();
    if (t == 0) bsum[blockIdx.x] = ws[0] + ws[1] + ws[2] + ws[3];
}

__global__ __launch_bounds__(1024) void scan_bsums(
    const int* __restrict__ bsum, int* boff, int nb)
{
    __shared__ int s[1024];
    int t = threadIdx.x;
    int v = (t < nb) ? bsum[t] : 0;
    s[t] = v;
    __syncthreads();
    for (int off = 1; off < 1024; off <<= 1) {
        int u = (t >= off) ? s[t - off] : 0;
        __syncthreads();
        s[t] += u;
        __syncthreads();
    }
    if (t < nb) boff[t] = s[t] - v;
}

__global__ __launch_bounds__(256) void scan_final(
    const int* __restrict__ hist, const int* __restrict__ boff,
    int* row_ptr, int* cursor, int N, int E)
{
    int t = threadIdx.x;
    int idx = blockIdx.x * STILE + t * 4;
    int4 v = make_int4(0, 0, 0, 0);
    if (idx + 3 < N) v = *reinterpret_cast<const int4*>(hist + idx);
    else {
        if (idx + 0 < N) v.x = hist[idx + 0];
        if (idx + 1 < N) v.y = hist[idx + 1];
        if (idx + 2 < N) v.z = hist[idx + 2];
        if (idx + 3 < N) v.w = hist[idx + 3];
    }
    int tsum = v.x + v.y + v.z + v.w;
    int lane = t & 63, wv = t >> 6;
    int incl = tsum;
    #pragma unroll
    for (int off = 1; off < 64; off <<= 1) {
        int u = __shfl_up(incl, off, 64);
        if (lane >= off) incl += u;
    }
    __shared__ int wsum[4];
    if (lane == 63) wsum[wv] = incl;
    __syncthreads();
    int woff = 0;
    for (int w = 0; w < wv; ++w) woff += wsum[w];
    int excl = woff + (incl - tsum) + boff[blockIdx.x];
    int4 rp;
    rp.x = excl;
    rp.y = excl + v.x;
    rp.z = rp.y + v.y;
    rp.w = rp.z + v.z;
    if (idx + 3 < N) {
        *reinterpret_cast<int4*>(row_ptr + idx) = rp;
        *reinterpret_cast<int4*>(cursor + idx) = rp;
    } else {
        if (idx + 0 < N) { row_ptr[idx + 0] = rp.x; cursor[idx + 0] = rp.x; }
        if (idx + 1 < N) { row_ptr[idx + 1] = rp.y; cursor[idx + 1] = rp.y; }
        if (idx + 2 < N) { row_ptr[idx + 2] = rp.z; cursor[idx + 2] = rp.z; }
        if (idx + 3 < N) { row_ptr[idx + 3] = rp.w; cursor[idx + 3] = rp.w; }
    }
    if (blockIdx.x == 0 && t == 0) row_ptr[N] = E;
}

__global__ __launch_bounds__(256) void sage_fill(
    const int* __restrict__ ei, int* cursor, int* perm, int E)
{
    int e = blockIdx.x * 256 + threadIdx.x;
    if (e < E) {
        int c = ei[E + e];
        int p = atomicAdd(&cursor[c], 1);
        perm[p] = ei[e];   // source row of this edge
    }
}

// ---------------- gather: out[i] = mean_{e in N(i)} x[src(e)] ---------------
__global__ __launch_bounds__(256) void sage_gather(
    const float* __restrict__ x,
    const int* __restrict__ row_ptr,
    const int* __restrict__ perm,
    float* out, int N)
{
    int wave = threadIdx.x >> 6;
    int lane = threadIdx.x & 63;
    int node = blockIdx.x * 4 + wave;
    if (node >= N) return;
    int start = row_ptr[node], end = row_ptr[node + 1];
    int half = lane >> 5, hl = lane & 31;
    float4 acc = make_float4(0.f, 0.f, 0.f, 0.f);
    for (int e = start + half; e < end; e += 2) {
        int r = perm[e];
        float4 v = reinterpret_cast<const float4*>(x)[(size_t)r * 32 + hl];
        acc.x += v.x; acc.y += v.y; acc.z += v.z; acc.w += v.w;
    }
    acc.x += __shfl_xor(acc.x, 32, 64);
    acc.y += __shfl_xor(acc.y, 32, 64);
    acc.z += __shfl_xor(acc.z, 32, 64);
    acc.w += __shfl_xor(acc.w, 32, 64);
    float sc = 1.0f / fmaxf((float)(end - start), 1.0f);
    if (half == 0) {
        reinterpret_cast<float4*>(out)[(size_t)node * 32 + hl] =
            make_float4(acc.x * sc, acc.y * sc, acc.z * sc, acc.w * sc);
    }
}

// ---------------- transform (MFMA): out = normalize([mean|x]@[Wrel|Wroot]^T + b)
// 3-term bf16 hi/lo split for fp32 accuracy. No LDS; W frags from L1/L2.
// Frag layout (16x16x32): a/b lane l -> row/col = l&15, k = (l>>4)*8 + e.
// C/D: col = lane&15, row = (lane>>4)*4 + reg  [m89-verified].
__global__ __launch_bounds__(256, 2) void sage_transform_mfma(
    float* inout,                 // mean in -> normalized out (in-place)
    const float* __restrict__ xg,
    const unsigned short* __restrict__ Whi,
    const unsigned short* __restrict__ Wlo,
    const float* __restrict__ brel, int N)
{
    const int lane = threadIdx.x & 63;
    const int wv   = threadIdx.x >> 6;
    const int l15  = lane & 15;
    const int koff = (lane >> 4) * 8;          // k sub-offset 0/8/16/24
    const int tbase = blockIdx.x * 64 + wv * 16;
    const int m_eff = min(tbase + l15, N - 1); // A-row this lane feeds

    const float* am = inout + (size_t)m_eff * D;   // mean half (k 0..127)
    const float* ax = xg    + (size_t)m_eff * D;   // x half    (k 128..255)

    f32x4 acc[8];
    #pragma unroll
    for (int nt = 0; nt < 8; ++nt) acc[nt] = (f32x4){0.f, 0.f, 0.f, 0.f};

    #pragma unroll
    for (int kb = 0; kb < 8; ++kb) {
        const float* src = (kb < 4) ? (am + kb * 32 + koff)
                                    : (ax + (kb - 4) * 32 + koff);
        float4 f0 = *reinterpret_cast<const float4*>(src);
        float4 f1 = *reinterpret_cast<const float4*>(src + 4);
        float fv[8] = {f0.x, f0.y, f0.z, f0.w, f1.x, f1.y, f1.z, f1.w};
        short8 ah, al;
        #pragma unroll
        for (int e = 0; e < 8; ++e) {
            unsigned short h = f2bf(fv[e]);
            ah[e] = (short)h;
            al[e] = (short)f2bf(fv[e] - bf2f(h));
        }
        const int krow = kb * 32 + koff;
        #pragma unroll
        for (int nt = 0; nt < 8; ++nt) {
            const unsigned short* wp = Whi + (size_t)(nt * 16 + l15) * 256 + krow;
            const unsigned short* lp = Wlo + (size_t)(nt * 16 + l15) * 256 + krow;
            short8 bh = *reinterpret_cast<const short8*>(wp);
            short8 bl = *reinterpret_cast<const short8*>(lp);
            acc[nt] = __builtin_amdgcn_mfma_f32_16x16x32_bf16(ah, bh, acc[nt], 0, 0, 0);
            acc[nt] = __builtin_amdgcn_mfma_f32_16x16x32_bf16(ah, bl, acc[nt], 0, 0, 0);
            acc[nt] = __builtin_amdgcn_mfma_f32_16x16x32_bf16(al, bh, acc[nt], 0, 0, 0);
        }
    }

    float bias[8];
    #pragma unroll
    for (int nt = 0; nt < 8; ++nt) bias[nt] = brel[nt * 16 + l15];

    // per C-reg r: row (lane>>4)*4 + r; 16-lane group holds all 128 cols
    #pragma unroll
    for (int r = 0; r < 4; ++r) {
        float ss = 0.f;
        #pragma unroll
        for (int nt = 0; nt < 8; ++nt) {
            float a = acc[nt][r] + bias[nt];
            acc[nt][r] = a;
            ss = fmaf(a, a, ss);
        }
        ss += __shfl_xor(ss, 1, 64);
        ss += __shfl_xor(ss, 2, 64);
        ss += __shfl_xor(ss, 4, 64);
        ss += __shfl_xor(ss, 8, 64);
        float inv = 1.0f / fmaxf(sqrtf(ss), 1e-12f);
        int row = tbase + (lane >> 4) * 4 + r;
        if (row < N) {
            float* o = inout + (size_t)row * D + l15;
            #pragma unroll
            for (int nt = 0; nt < 8; ++nt)
                o[nt * 16] = acc[nt][r] * inv;
        }
    }
}

extern "C" void kernel_launch(void* const* d_in, const int* in_sizes, int n_in,
                              void* d_out, int out_size, void* d_ws, size_t ws_size,
                              hipStream_t stream)
{
    const float* x    = (const float*)d_in[0];
    const int*   ei   = (const int*)d_in[2];
    const float* Wrel = (const float*)d_in[3];
    const float* brel = (const float*)d_in[4];
    const float* Wroot= (const float*)d_in[5];
    int N = in_sizes[0] / D;
    int E = in_sizes[2] / 2;
    float* out = (float*)d_out;

    int nb = (N + STILE - 1) / STILE;

    // ws layout: Whi[32768] Wlo[32768] (ushort, 16B-aligned) |
    //            hist[N] row_ptr[N+1] cursor[N] bsum[nb] boff[nb] perm[E] (int)
    unsigned short* Whi = (unsigned short*)d_ws;
    unsigned short* Wlo = Whi + 32768;
    int* hist    = (int*)(Wlo + 32768);
    int* row_ptr = hist + N;
    int* cursor  = row_ptr + N + 1;
    int* bsum    = cursor + N;
    int* boff    = bsum + nb;
    int* perm    = boff + nb;

    hipMemsetAsync(hist, 0, (size_t)N * sizeof(int), stream);

    sage_wprep<<<128, 256, 0, stream>>>(Wrel, Wroot, Whi, Wlo);

    int eblocks = (E + 255) / 256;
    sage_hist<<<eblocks, 256, 0, stream>>>(ei, hist, E);
    scan_partial<<<nb, 256, 0, stream>>>(hist, bsum, N);
    scan_bsums<<<1, 1024, 0, stream>>>(bsum, boff, nb);
    scan_final<<<nb, 256, 0, stream>>>(hist, boff, row_ptr, cursor, N, E);
    sage_fill<<<eblocks, 256, 0, stream>>>(ei, cursor, perm, E);
    sage_gather<<<(N + 3) / 4, 256, 0, stream>>>(x, row_ptr, perm, out, N);

    sage_transform_mfma<<<(N + 63) / 64, 256, 0, stream>>>(
        out, x, Whi, Wlo, brel, N);
}

// Round 6
// 395.789 us; speedup vs baseline: 7.7623x; 1.3656x over previous
//
#include <hip/hip_runtime.h>
#include <cstdint>

#define D 128
#define NBMAX 128      // max buckets (requires N <= 131072 for 17-bit rows)
#define BSH 10         // 1024 nodes per bucket
#define PASSA_TILE 4096
#define PASSA_VT 16
#define CAPB 32768     // pass-B LDS perm capacity (entries)

using short8 = __attribute__((ext_vector_type(8))) short;
using f32x4  = __attribute__((ext_vector_type(4))) float;

// fp32 -> bf16 bits, round-to-nearest-even
__device__ inline unsigned short f2bf(float f) {
    unsigned u = __float_as_uint(f);
    return (unsigned short)((u + 0x7FFFu + ((u >> 16) & 1u)) >> 16);
}
__device__ inline float bf2f(unsigned short h) {
    return __uint_as_float(((unsigned)h) << 16);
}

// ---------------- W prep: [Wrel | Wroot] -> bf16 hi/lo, row-major [128][256]
__global__ __launch_bounds__(256) void sage_wprep(
    const float* __restrict__ Wrel, const float* __restrict__ Wroot,
    unsigned short* Whi, unsigned short* Wlo)
{
    int t = blockIdx.x * 256 + threadIdx.x;   // 0..32767
    int j = t >> 8, k = t & 255;
    float f = (k < 128) ? Wrel[j * 128 + k] : Wroot[j * 128 + (k - 128)];
    unsigned short hi = f2bf(f);
    Whi[t] = hi;
    Wlo[t] = f2bf(f - bf2f(hi));
}

// ================= CSR build, LDS-staged two-level counting sort ============
// 1) coarse bucket histogram (LDS-privatized)
__global__ __launch_bounds__(256) void bucket_hist(
    const int* __restrict__ col, int* gbh, int E, int nbuck)
{
    __shared__ int h[NBMAX];
    for (int i = threadIdx.x; i < NBMAX; i += 256) h[i] = 0;
    __syncthreads();
    int stride = gridDim.x * 256;
    for (int e = blockIdx.x * 256 + threadIdx.x; e < E; e += stride)
        atomicAdd(&h[col[e] >> BSH], 1);
    __syncthreads();
    for (int i = threadIdx.x; i < nbuck; i += 256)
        if (h[i]) atomicAdd(&gbh[i], h[i]);
}

// 2) exclusive scan of bucket counts -> boff, gcur (single block, NBMAX thr)
__global__ __launch_bounds__(NBMAX) void bucket_scan(
    const int* __restrict__ gbh, int* boff, int* gcur, int nbuck)
{
    __shared__ int s[NBMAX];
    int t = threadIdx.x;
    int v = (t < nbuck) ? gbh[t] : 0;
    s[t] = v;
    __syncthreads();
    for (int off = 1; off < NBMAX; off <<= 1) {
        int u = (t >= off) ? s[t - off] : 0;
        __syncthreads();
        s[t] += u;
        __syncthreads();
    }
    if (t < nbuck) { int e = s[t] - v; boff[t] = e; gcur[t] = e; }
}

// 3) bucketize edges: LDS-rank each 4096-edge tile by bucket, copy out
//    contiguous runs per bucket. Entry = (col_low << 17) | row  (4B).
__global__ __launch_bounds__(256) void bucketize(
    const int* __restrict__ ei, int* gcur, unsigned* bucketed, int E, int nbuck)
{
    __shared__ int hcnt[NBMAX];
    __shared__ int hoff[NBMAX];   // scan buffer
    __shared__ int cur[NBMAX];
    __shared__ int gbase[NBMAX];
    __shared__ unsigned staged[PASSA_TILE];

    int t = threadIdx.x;
    int base = blockIdx.x * PASSA_TILE;

    for (int i = t; i < NBMAX; i += 256) hcnt[i] = 0;
    __syncthreads();

    int myb[PASSA_VT];
    unsigned mypk[PASSA_VT];
    #pragma unroll
    for (int k = 0; k < PASSA_VT; ++k) {
        int e = base + k * 256 + t;
        if (e < E) {
            int c = ei[E + e];
            int r = ei[e];
            int b = c >> BSH;
            myb[k] = b;
            mypk[k] = ((unsigned)(c & ((1 << BSH) - 1)) << 17) | (unsigned)r;
            atomicAdd(&hcnt[b], 1);
        } else myb[k] = -1;
    }
    __syncthreads();

    // inclusive scan of hcnt into hoff (all threads hit barriers)
    if (t < NBMAX) hoff[t] = hcnt[t];
    __syncthreads();
    for (int off = 1; off < NBMAX; off <<= 1) {
        int u = 0;
        if (t < NBMAX && t >= off) u = hoff[t - off];
        __syncthreads();
        if (t < NBMAX) hoff[t] += u;
        __syncthreads();
    }
    if (t < NBMAX) cur[t] = hoff[t] - hcnt[t];   // exclusive
    __syncthreads();

    #pragma unroll
    for (int k = 0; k < PASSA_VT; ++k) {
        if (myb[k] >= 0) {
            int pos = atomicAdd(&cur[myb[k]], 1);
            staged[pos] = mypk[k];
        }
    }
    __syncthreads();

    if (t < nbuck && hcnt[t] > 0)
        gbase[t] = atomicAdd(&gcur[t], hcnt[t]);
    __syncthreads();

    if (t < nbuck) {
        int cnt = hcnt[t];
        int lo = cur[t] - cnt;   // cur advanced by cnt during placement
        int gb = gbase[t];
        for (int i = 0; i < cnt; ++i)
            bucketed[gb + i] = staged[lo + i];
    }
}

// 4) per-bucket local CSR: node hist + scan in LDS, write row_ptr slice,
//    place perm in LDS, stream out coalesced.
__global__ __launch_bounds__(256, 1) void bucket_csr(
    const unsigned* __restrict__ bucketed,
    const int* __restrict__ gbh, const int* __restrict__ boff,
    int* row_ptr, int* perm, int N, int E)
{
    __shared__ int lcur[1 << BSH];       // hist -> cursors
    __shared__ int wtot[4];
    __shared__ int lperm_s[CAPB];        // 128 KiB

    int b = blockIdx.x;
    int t = threadIdx.x;
    int lane = t & 63, wv = t >> 6;
    int base = boff[b];
    int count = gbh[b];
    int node0 = b << BSH;
    int nnodes = min(1 << BSH, N - node0);

    for (int i = t; i < (1 << BSH); i += 256) lcur[i] = 0;
    __syncthreads();
    for (int i = t; i < count; i += 256)
        atomicAdd(&lcur[bucketed[base + i] >> 17], 1);
    __syncthreads();

    // scan nnodes (<=1024) entries, 4 per thread
    int loc[4];
    int run = 0;
    #pragma unroll
    for (int k = 0; k < 4; ++k) {
        int idx = t * 4 + k;
        loc[k] = run;
        run += (idx < nnodes) ? lcur[idx] : 0;
    }
    int incl = run;
    #pragma unroll
    for (int off = 1; off < 64; off <<= 1) {
        int u = __shfl_up(incl, off, 64);
        if (lane >= off) incl += u;
    }
    if (lane == 63) wtot[wv] = incl;
    __syncthreads();
    int woff = 0;
    for (int w = 0; w < wv; ++w) woff += wtot[w];
    int texcl = woff + (incl - run);
    __syncthreads();           // all hist reads done before overwrite
    #pragma unroll
    for (int k = 0; k < 4; ++k) {
        int idx = t * 4 + k;
        if (idx < nnodes) {
            int ex = texcl + loc[k];
            row_ptr[node0 + idx] = base + ex;
            lcur[idx] = ex;    // local cursor
        }
    }
    if (t == 0 && node0 + nnodes == N) row_ptr[N] = base + count;
    __syncthreads();

    if (count <= CAPB) {
        for (int i = t; i < count; i += 256) {
            unsigned pk = bucketed[base + i];
            int pos = atomicAdd(&lcur[pk >> 17], 1);
            lperm_s[pos] = (int)(pk & 0x1FFFF);
        }
        __syncthreads();
        for (int i = t; i < count; i += 256)
            perm[base + i] = lperm_s[i];
    } else {                   // overflow fallback (correct, amplified)
        for (int i = t; i < count; i += 256) {
            unsigned pk = bucketed[base + i];
            int pos = atomicAdd(&lcur[pk >> 17], 1);
            perm[base + pos] = (int)(pk & 0x1FFFF);
        }
    }
}

// ================= emergency old path (ws too small / N too big) ===========
__global__ __launch_bounds__(256) void sage_hist_old(
    const int* __restrict__ ei, int* hist, int E)
{
    int e = blockIdx.x * 256 + threadIdx.x;
    if (e < E) atomicAdd(&hist[ei[E + e]], 1);
}
__global__ __launch_bounds__(1024) void sage_scan_old(
    const int* __restrict__ hist, int* row_ptr, int* cursor, int N)
{
    __shared__ int s[1024];
    int t = threadIdx.x;
    int chunk = (N + 1023) / 1024;
    int lo = t * chunk, hi = min(lo + chunk, N);
    int sum = 0;
    for (int i = lo; i < hi; ++i) sum += hist[i];
    s[t] = sum;
    __syncthreads();
    for (int off = 1; off < 1024; off <<= 1) {
        int v = (t >= off) ? s[t - off] : 0;
        __syncthreads();
        s[t] += v;
        __syncthreads();
    }
    int p = s[t] - sum;
    for (int i = lo; i < hi; ++i) {
        row_ptr[i] = p; cursor[i] = p; p += hist[i];
    }
    if (t == 1023) row_ptr[N] = s[1023];
}
__global__ __launch_bounds__(256) void sage_fill_old(
    const int* __restrict__ ei, int* cursor, int* perm, int E)
{
    int e = blockIdx.x * 256 + threadIdx.x;
    if (e < E) {
        int p = atomicAdd(&cursor[ei[E + e]], 1);
        perm[p] = ei[e];
    }
}

// ---------------- gather: out[i] = mean_{e in N(i)} x[src(e)] ---------------
__global__ __launch_bounds__(256) void sage_gather(
    const float* __restrict__ x,
    const int* __restrict__ row_ptr,
    const int* __restrict__ perm,
    float* out, int N)
{
    int wave = threadIdx.x >> 6;
    int lane = threadIdx.x & 63;
    int node = blockIdx.x * 4 + wave;
    if (node >= N) return;
    int start = row_ptr[node], end = row_ptr[node + 1];
    int half = lane >> 5, hl = lane & 31;
    float4 acc = make_float4(0.f, 0.f, 0.f, 0.f);
    for (int e = start + half; e < end; e += 2) {
        int r = perm[e];
        float4 v = reinterpret_cast<const float4*>(x)[(size_t)r * 32 + hl];
        acc.x += v.x; acc.y += v.y; acc.z += v.z; acc.w += v.w;
    }
    acc.x += __shfl_xor(acc.x, 32, 64);
    acc.y += __shfl_xor(acc.y, 32, 64);
    acc.z += __shfl_xor(acc.z, 32, 64);
    acc.w += __shfl_xor(acc.w, 32, 64);
    float sc = 1.0f / fmaxf((float)(end - start), 1.0f);
    if (half == 0) {
        reinterpret_cast<float4*>(out)[(size_t)node * 32 + hl] =
            make_float4(acc.x * sc, acc.y * sc, acc.z * sc, acc.w * sc);
    }
}

// ---------------- transform (MFMA): out = normalize([mean|x]@[Wrel|Wroot]^T + b)
__global__ __launch_bounds__(256, 2) void sage_transform_mfma(
    float* inout,
    const float* __restrict__ xg,
    const unsigned short* __restrict__ Whi,
    const unsigned short* __restrict__ Wlo,
    const float* __restrict__ brel, int N)
{
    const int lane = threadIdx.x & 63;
    const int wv   = threadIdx.x >> 6;
    const int l15  = lane & 15;
    const int koff = (lane >> 4) * 8;
    const int tbase = blockIdx.x * 64 + wv * 16;
    const int m_eff = min(tbase + l15, N - 1);

    const float* am = inout + (size_t)m_eff * D;
    const float* ax = xg    + (size_t)m_eff * D;

    f32x4 acc[8];
    #pragma unroll
    for (int nt = 0; nt < 8; ++nt) acc[nt] = (f32x4){0.f, 0.f, 0.f, 0.f};

    #pragma unroll
    for (int kb = 0; kb < 8; ++kb) {
        const float* src = (kb < 4) ? (am + kb * 32 + koff)
                                    : (ax + (kb - 4) * 32 + koff);
        float4 f0 = *reinterpret_cast<const float4*>(src);
        float4 f1 = *reinterpret_cast<const float4*>(src + 4);
        float fv[8] = {f0.x, f0.y, f0.z, f0.w, f1.x, f1.y, f1.z, f1.w};
        short8 ah, al;
        #pragma unroll
        for (int e = 0; e < 8; ++e) {
            unsigned short h = f2bf(fv[e]);
            ah[e] = (short)h;
            al[e] = (short)f2bf(fv[e] - bf2f(h));
        }
        const int krow = kb * 32 + koff;
        #pragma unroll
        for (int nt = 0; nt < 8; ++nt) {
            const unsigned short* wp = Whi + (size_t)(nt * 16 + l15) * 256 + krow;
            const unsigned short* lp = Wlo + (size_t)(nt * 16 + l15) * 256 + krow;
            short8 bh = *reinterpret_cast<const short8*>(wp);
            short8 bl = *reinterpret_cast<const short8*>(lp);
            acc[nt] = __builtin_amdgcn_mfma_f32_16x16x32_bf16(ah, bh, acc[nt], 0, 0, 0);
            acc[nt] = __builtin_amdgcn_mfma_f32_16x16x32_bf16(ah, bl, acc[nt], 0, 0, 0);
            acc[nt] = __builtin_amdgcn_mfma_f32_16x16x32_bf16(al, bh, acc[nt], 0, 0, 0);
        }
    }

    float bias[8];
    #pragma unroll
    for (int nt = 0; nt < 8; ++nt) bias[nt] = brel[nt * 16 + l15];

    #pragma unroll
    for (int r = 0; r < 4; ++r) {
        float ss = 0.f;
        #pragma unroll
        for (int nt = 0; nt < 8; ++nt) {
            float a = acc[nt][r] + bias[nt];
            acc[nt][r] = a;
            ss = fmaf(a, a, ss);
        }
        ss += __shfl_xor(ss, 1, 64);
        ss += __shfl_xor(ss, 2, 64);
        ss += __shfl_xor(ss, 4, 64);
        ss += __shfl_xor(ss, 8, 64);
        float inv = 1.0f / fmaxf(sqrtf(ss), 1e-12f);
        int row = tbase + (lane >> 4) * 4 + r;
        if (row < N) {
            float* o = inout + (size_t)row * D + l15;
            #pragma unroll
            for (int nt = 0; nt < 8; ++nt)
                o[nt * 16] = acc[nt][r] * inv;
        }
    }
}

extern "C" void kernel_launch(void* const* d_in, const int* in_sizes, int n_in,
                              void* d_out, int out_size, void* d_ws, size_t ws_size,
                              hipStream_t stream)
{
    const float* x    = (const float*)d_in[0];
    const int*   ei   = (const int*)d_in[2];
    const float* Wrel = (const float*)d_in[3];
    const float* brel = (const float*)d_in[4];
    const float* Wroot= (const float*)d_in[5];
    int N = in_sizes[0] / D;
    int E = in_sizes[2] / 2;
    float* out = (float*)d_out;

    unsigned short* Whi = (unsigned short*)d_ws;
    unsigned short* Wlo = Whi + 32768;

    sage_wprep<<<128, 256, 0, stream>>>(Wrel, Wroot, Whi, Wlo);

    int nbuck = (N + (1 << BSH) - 1) >> BSH;
    int* gbh     = (int*)(Wlo + 32768);
    int* boff    = gbh + NBMAX;
    int* gcur    = boff + NBMAX;
    int* row_ptr = gcur + NBMAX;
    unsigned* bucketed = (unsigned*)(row_ptr + N + 1);
    int* perm    = (int*)(bucketed + E);
    size_t need  = (size_t)((char*)(perm + E) - (char*)d_ws);

    if (N <= (1 << 17) && nbuck <= NBMAX && need <= ws_size) {
        hipMemsetAsync(gbh, 0, NBMAX * sizeof(int), stream);
        bucket_hist<<<256, 256, 0, stream>>>(ei + E, gbh, E, nbuck);
        bucket_scan<<<1, NBMAX, 0, stream>>>(gbh, boff, gcur, nbuck);
        bucketize<<<(E + PASSA_TILE - 1) / PASSA_TILE, 256, 0, stream>>>(
            ei, gcur, bucketed, E, nbuck);
        bucket_csr<<<nbuck, 256, 0, stream>>>(
            bucketed, gbh, boff, row_ptr, perm, N, E);
        sage_gather<<<(N + 3) / 4, 256, 0, stream>>>(x, row_ptr, perm, out, N);
    } else {
        // emergency path (layout as in R4)
        int* hist    = (int*)(Wlo + 32768);
        int* rp      = hist + N;
        int* cursor  = rp + N + 1;
        int* perm2   = cursor + N;
        hipMemsetAsync(hist, 0, (size_t)N * sizeof(int), stream);
        int eblocks = (E + 255) / 256;
        sage_hist_old<<<eblocks, 256, 0, stream>>>(ei, hist, E);
        sage_scan_old<<<1, 1024, 0, stream>>>(hist, rp, cursor, N);
        sage_fill_old<<<eblocks, 256, 0, stream>>>(ei, cursor, perm2, E);
        sage_gather<<<(N + 3) / 4, 256, 0, stream>>>(x, rp, perm2, out, N);
    }

    sage_transform_mfma<<<(N + 63) / 64, 256, 0, stream>>>(
        out, x, Whi, Wlo, brel, N);
}

// Round 7
// 327.223 us; speedup vs baseline: 9.3888x; 1.2095x over previous
//
#include <hip/hip_runtime.h>
#include <cstdint>

#define D 128
#define NBMAX 128      // max buckets (requires N <= 131072 for 17-bit rows)
#define BSH 10         // 1024 nodes per bucket
#define PASSA_TILE 4096
#define PASSA_VT 16
#define CAPB 32768     // pass-B LDS perm capacity (entries)

using short8 = __attribute__((ext_vector_type(8))) short;
using f32x4  = __attribute__((ext_vector_type(4))) float;

// fp32 -> bf16 bits, round-to-nearest-even
__device__ inline unsigned short f2bf(float f) {
    unsigned u = __float_as_uint(f);
    return (unsigned short)((u + 0x7FFFu + ((u >> 16) & 1u)) >> 16);
}
__device__ inline float bf2f(unsigned short h) {
    return __uint_as_float(((unsigned)h) << 16);
}

// ---------------- W prep: [Wrel | Wroot] -> bf16 hi/lo, row-major [128][256]
__global__ __launch_bounds__(256) void sage_wprep(
    const float* __restrict__ Wrel, const float* __restrict__ Wroot,
    unsigned short* Whi, unsigned short* Wlo)
{
    int t = blockIdx.x * 256 + threadIdx.x;   // 0..32767
    int j = t >> 8, k = t & 255;
    float f = (k < 128) ? Wrel[j * 128 + k] : Wroot[j * 128 + (k - 128)];
    unsigned short hi = f2bf(f);
    Whi[t] = hi;
    Wlo[t] = f2bf(f - bf2f(hi));
}

// ---------------- x -> bf16 (for gather only) -------------------------------
__global__ __launch_bounds__(256) void sage_xprep(
    const float* __restrict__ x, unsigned short* xbf, long long total8)
{
    long long t = (long long)blockIdx.x * 256 + threadIdx.x;  // one per 8 elems
    if (t >= total8) return;
    const float4* src = reinterpret_cast<const float4*>(x) + t * 2;
    float4 f0 = src[0], f1 = src[1];
    short8 v;
    v[0] = (short)f2bf(f0.x); v[1] = (short)f2bf(f0.y);
    v[2] = (short)f2bf(f0.z); v[3] = (short)f2bf(f0.w);
    v[4] = (short)f2bf(f1.x); v[5] = (short)f2bf(f1.y);
    v[6] = (short)f2bf(f1.z); v[7] = (short)f2bf(f1.w);
    *reinterpret_cast<short8*>(xbf + t * 8) = v;
}

// ================= CSR build, LDS-staged two-level counting sort ============
__global__ __launch_bounds__(256) void bucket_hist(
    const int* __restrict__ col, int* gbh, int E, int nbuck)
{
    __shared__ int h[NBMAX];
    for (int i = threadIdx.x; i < NBMAX; i += 256) h[i] = 0;
    __syncthreads();
    int stride = gridDim.x * 256;
    for (int e = blockIdx.x * 256 + threadIdx.x; e < E; e += stride)
        atomicAdd(&h[col[e] >> BSH], 1);
    __syncthreads();
    for (int i = threadIdx.x; i < nbuck; i += 256)
        if (h[i]) atomicAdd(&gbh[i], h[i]);
}

__global__ __launch_bounds__(NBMAX) void bucket_scan(
    const int* __restrict__ gbh, int* boff, int* gcur, int nbuck)
{
    __shared__ int s[NBMAX];
    int t = threadIdx.x;
    int v = (t < nbuck) ? gbh[t] : 0;
    s[t] = v;
    __syncthreads();
    for (int off = 1; off < NBMAX; off <<= 1) {
        int u = (t >= off) ? s[t - off] : 0;
        __syncthreads();
        s[t] += u;
        __syncthreads();
    }
    if (t < nbuck) { int e = s[t] - v; boff[t] = e; gcur[t] = e; }
}

__global__ __launch_bounds__(256) void bucketize(
    const int* __restrict__ ei, int* gcur, unsigned* bucketed, int E, int nbuck)
{
    __shared__ int hcnt[NBMAX];
    __shared__ int hoff[NBMAX];
    __shared__ int cur[NBMAX];
    __shared__ int gbase[NBMAX];
    __shared__ unsigned staged[PASSA_TILE];

    int t = threadIdx.x;
    int base = blockIdx.x * PASSA_TILE;

    for (int i = t; i < NBMAX; i += 256) hcnt[i] = 0;
    __syncthreads();

    int myb[PASSA_VT];
    unsigned mypk[PASSA_VT];
    #pragma unroll
    for (int k = 0; k < PASSA_VT; ++k) {
        int e = base + k * 256 + t;
        if (e < E) {
            int c = ei[E + e];
            int r = ei[e];
            int b = c >> BSH;
            myb[k] = b;
            mypk[k] = ((unsigned)(c & ((1 << BSH) - 1)) << 17) | (unsigned)r;
            atomicAdd(&hcnt[b], 1);
        } else myb[k] = -1;
    }
    __syncthreads();

    if (t < NBMAX) hoff[t] = hcnt[t];
    __syncthreads();
    for (int off = 1; off < NBMAX; off <<= 1) {
        int u = 0;
        if (t < NBMAX && t >= off) u = hoff[t - off];
        __syncthreads();
        if (t < NBMAX) hoff[t] += u;
        __syncthreads();
    }
    if (t < NBMAX) cur[t] = hoff[t] - hcnt[t];
    __syncthreads();

    #pragma unroll
    for (int k = 0; k < PASSA_VT; ++k) {
        if (myb[k] >= 0) {
            int pos = atomicAdd(&cur[myb[k]], 1);
            staged[pos] = mypk[k];
        }
    }
    __syncthreads();

    if (t < nbuck && hcnt[t] > 0)
        gbase[t] = atomicAdd(&gcur[t], hcnt[t]);
    __syncthreads();

    if (t < nbuck) {
        int cnt = hcnt[t];
        int lo = cur[t] - cnt;
        int gb = gbase[t];
        for (int i = 0; i < cnt; ++i)
            bucketed[gb + i] = staged[lo + i];
    }
}

__global__ __launch_bounds__(256, 1) void bucket_csr(
    const unsigned* __restrict__ bucketed,
    const int* __restrict__ gbh, const int* __restrict__ boff,
    int* row_ptr, int* perm, int N, int E)
{
    __shared__ int lcur[1 << BSH];
    __shared__ int wtot[4];
    __shared__ int lperm_s[CAPB];

    int b = blockIdx.x;
    int t = threadIdx.x;
    int lane = t & 63, wv = t >> 6;
    int base = boff[b];
    int count = gbh[b];
    int node0 = b << BSH;
    int nnodes = min(1 << BSH, N - node0);

    for (int i = t; i < (1 << BSH); i += 256) lcur[i] = 0;
    __syncthreads();
    for (int i = t; i < count; i += 256)
        atomicAdd(&lcur[bucketed[base + i] >> 17], 1);
    __syncthreads();

    int loc[4];
    int run = 0;
    #pragma unroll
    for (int k = 0; k < 4; ++k) {
        int idx = t * 4 + k;
        loc[k] = run;
        run += (idx < nnodes) ? lcur[idx] : 0;
    }
    int incl = run;
    #pragma unroll
    for (int off = 1; off < 64; off <<= 1) {
        int u = __shfl_up(incl, off, 64);
        if (lane >= off) incl += u;
    }
    if (lane == 63) wtot[wv] = incl;
    __syncthreads();
    int woff = 0;
    for (int w = 0; w < wv; ++w) woff += wtot[w];
    int texcl = woff + (incl - run);
    __syncthreads();
    #pragma unroll
    for (int k = 0; k < 4; ++k) {
        int idx = t * 4 + k;
        if (idx < nnodes) {
            int ex = texcl + loc[k];
            row_ptr[node0 + idx] = base + ex;
            lcur[idx] = ex;
        }
    }
    if (t == 0 && node0 + nnodes == N) row_ptr[N] = base + count;
    __syncthreads();

    if (count <= CAPB) {
        for (int i = t; i < count; i += 256) {
            unsigned pk = bucketed[base + i];
            int pos = atomicAdd(&lcur[pk >> 17], 1);
            lperm_s[pos] = (int)(pk & 0x1FFFF);
        }
        __syncthreads();
        for (int i = t; i < count; i += 256)
            perm[base + i] = lperm_s[i];
    } else {
        for (int i = t; i < count; i += 256) {
            unsigned pk = bucketed[base + i];
            int pos = atomicAdd(&lcur[pk >> 17], 1);
            perm[base + pos] = (int)(pk & 0x1FFFF);
        }
    }
}

// ================= emergency old path ======================================
__global__ __launch_bounds__(256) void sage_hist_old(
    const int* __restrict__ ei, int* hist, int E)
{
    int e = blockIdx.x * 256 + threadIdx.x;
    if (e < E) atomicAdd(&hist[ei[E + e]], 1);
}
__global__ __launch_bounds__(1024) void sage_scan_old(
    const int* __restrict__ hist, int* row_ptr, int* cursor, int N)
{
    __shared__ int s[1024];
    int t = threadIdx.x;
    int chunk = (N + 1023) / 1024;
    int lo = t * chunk, hi = min(lo + chunk, N);
    int sum = 0;
    for (int i = lo; i < hi; ++i) sum += hist[i];
    s[t] = sum;
    __syncthreads();
    for (int off = 1; off < 1024; off <<= 1) {
        int v = (t >= off) ? s[t - off] : 0;
        __syncthreads();
        s[t] += v;
        __syncthreads();
    }
    int p = s[t] - sum;
    for (int i = lo; i < hi; ++i) {
        row_ptr[i] = p; cursor[i] = p; p += hist[i];
    }
    if (t == 1023) row_ptr[N] = s[1023];
}
__global__ __launch_bounds__(256) void sage_fill_old(
    const int* __restrict__ ei, int* cursor, int* perm, int E)
{
    int e = blockIdx.x * 256 + threadIdx.x;
    if (e < E) {
        int p = atomicAdd(&cursor[ei[E + e]], 1);
        perm[p] = ei[e];
    }
}

// ---------------- gather (bf16 x): out[i] = mean_{e in N(i)} x[src(e)] ------
// 4 groups of 16 lanes; each group one edge; lane j covers feature cols j*8..j*8+7
__global__ __launch_bounds__(256) void sage_gather_bf(
    const unsigned short* __restrict__ xbf,
    const int* __restrict__ row_ptr,
    const int* __restrict__ perm,
    float* out, int N)
{
    int wave = threadIdx.x >> 6;
    int lane = threadIdx.x & 63;
    int node = blockIdx.x * 4 + wave;
    if (node >= N) return;
    int start = row_ptr[node], end = row_ptr[node + 1];
    int g = lane >> 4, j = lane & 15;
    float acc[8] = {0.f, 0.f, 0.f, 0.f, 0.f, 0.f, 0.f, 0.f};
    for (int e = start + g; e < end; e += 4) {
        int r = perm[e];
        short8 v = *reinterpret_cast<const short8*>(xbf + (size_t)r * D + j * 8);
        #pragma unroll
        for (int el = 0; el < 8; ++el)
            acc[el] += bf2f((unsigned short)v[el]);
    }
    #pragma unroll
    for (int el = 0; el < 8; ++el) {
        acc[el] += __shfl_xor(acc[el], 16, 64);
        acc[el] += __shfl_xor(acc[el], 32, 64);
    }
    if (g == 0) {
        float sc = 1.0f / fmaxf((float)(end - start), 1.0f);
        float4 w0 = make_float4(acc[0] * sc, acc[1] * sc, acc[2] * sc, acc[3] * sc);
        float4 w1 = make_float4(acc[4] * sc, acc[5] * sc, acc[6] * sc, acc[7] * sc);
        float4* o = reinterpret_cast<float4*>(out + (size_t)node * D + j * 8);
        o[0] = w0;
        o[1] = w1;
    }
}

// fp32 fallback gather
__global__ __launch_bounds__(256) void sage_gather(
    const float* __restrict__ x,
    const int* __restrict__ row_ptr,
    const int* __restrict__ perm,
    float* out, int N)
{
    int wave = threadIdx.x >> 6;
    int lane = threadIdx.x & 63;
    int node = blockIdx.x * 4 + wave;
    if (node >= N) return;
    int start = row_ptr[node], end = row_ptr[node + 1];
    int half = lane >> 5, hl = lane & 31;
    float4 acc = make_float4(0.f, 0.f, 0.f, 0.f);
    for (int e = start + half; e < end; e += 2) {
        int r = perm[e];
        float4 v = reinterpret_cast<const float4*>(x)[(size_t)r * 32 + hl];
        acc.x += v.x; acc.y += v.y; acc.z += v.z; acc.w += v.w;
    }
    acc.x += __shfl_xor(acc.x, 32, 64);
    acc.y += __shfl_xor(acc.y, 32, 64);
    acc.z += __shfl_xor(acc.z, 32, 64);
    acc.w += __shfl_xor(acc.w, 32, 64);
    float sc = 1.0f / fmaxf((float)(end - start), 1.0f);
    if (half == 0) {
        reinterpret_cast<float4*>(out)[(size_t)node * 32 + hl] =
            make_float4(acc.x * sc, acc.y * sc, acc.z * sc, acc.w * sc);
    }
}

// ---------------- transform (MFMA): out = normalize([mean|x]@[Wrel|Wroot]^T + b)
// 2 row-tiles (32 rows) per wave; A prefetched one kb ahead; 3-term hi/lo split.
__global__ __launch_bounds__(256, 2) void sage_transform_mfma(
    float* inout,
    const float* __restrict__ xg,
    const unsigned short* __restrict__ Whi,
    const unsigned short* __restrict__ Wlo,
    const float* __restrict__ brel, int N)
{
    const int lane = threadIdx.x & 63;
    const int wv   = threadIdx.x >> 6;
    const int l15  = lane & 15;
    const int koff = (lane >> 4) * 8;
    const int tbase = blockIdx.x * 128 + wv * 32;
    const int m0 = min(tbase + l15, N - 1);
    const int m1 = min(tbase + 16 + l15, N - 1);

    const float* am0 = inout + (size_t)m0 * D;
    const float* ax0 = xg    + (size_t)m0 * D;
    const float* am1 = inout + (size_t)m1 * D;
    const float* ax1 = xg    + (size_t)m1 * D;

    f32x4 acc0[8], acc1[8];
    #pragma unroll
    for (int nt = 0; nt < 8; ++nt) {
        acc0[nt] = (f32x4){0.f, 0.f, 0.f, 0.f};
        acc1[nt] = (f32x4){0.f, 0.f, 0.f, 0.f};
    }

    float4 c00, c01, c10, c11;   // raw A for current kb (tile0/tile1)
    c00 = *reinterpret_cast<const float4*>(am0 + koff);
    c01 = *reinterpret_cast<const float4*>(am0 + koff + 4);
    c10 = *reinterpret_cast<const float4*>(am1 + koff);
    c11 = *reinterpret_cast<const float4*>(am1 + koff + 4);

    #pragma unroll
    for (int kb = 0; kb < 8; ++kb) {
        // convert current raw A -> bf16 hi/lo frags
        float fv0[8] = {c00.x, c00.y, c00.z, c00.w, c01.x, c01.y, c01.z, c01.w};
        float fv1[8] = {c10.x, c10.y, c10.z, c10.w, c11.x, c11.y, c11.z, c11.w};
        short8 ah0, al0, ah1, al1;
        #pragma unroll
        for (int e = 0; e < 8; ++e) {
            unsigned short h0 = f2bf(fv0[e]);
            ah0[e] = (short)h0;
            al0[e] = (short)f2bf(fv0[e] - bf2f(h0));
            unsigned short h1 = f2bf(fv1[e]);
            ah1[e] = (short)h1;
            al1[e] = (short)f2bf(fv1[e] - bf2f(h1));
        }
        // prefetch next kb (independent; overlaps with MFMA below)
        if (kb < 7) {
            int nkb = kb + 1;
            const float* s0 = (nkb < 4) ? (am0 + nkb * 32 + koff)
                                        : (ax0 + (nkb - 4) * 32 + koff);
            const float* s1 = (nkb < 4) ? (am1 + nkb * 32 + koff)
                                        : (ax1 + (nkb - 4) * 32 + koff);
            c00 = *reinterpret_cast<const float4*>(s0);
            c01 = *reinterpret_cast<const float4*>(s0 + 4);
            c10 = *reinterpret_cast<const float4*>(s1);
            c11 = *reinterpret_cast<const float4*>(s1 + 4);
        }
        const int krow = kb * 32 + koff;
        #pragma unroll
        for (int nt = 0; nt < 8; ++nt) {
            const unsigned short* wp = Whi + (size_t)(nt * 16 + l15) * 256 + krow;
            const unsigned short* lp = Wlo + (size_t)(nt * 16 + l15) * 256 + krow;
            short8 bh = *reinterpret_cast<const short8*>(wp);
            short8 bl = *reinterpret_cast<const short8*>(lp);
            acc0[nt] = __builtin_amdgcn_mfma_f32_16x16x32_bf16(ah0, bh, acc0[nt], 0, 0, 0);
            acc0[nt] = __builtin_amdgcn_mfma_f32_16x16x32_bf16(ah0, bl, acc0[nt], 0, 0, 0);
            acc0[nt] = __builtin_amdgcn_mfma_f32_16x16x32_bf16(al0, bh, acc0[nt], 0, 0, 0);
            acc1[nt] = __builtin_amdgcn_mfma_f32_16x16x32_bf16(ah1, bh, acc1[nt], 0, 0, 0);
            acc1[nt] = __builtin_amdgcn_mfma_f32_16x16x32_bf16(ah1, bl, acc1[nt], 0, 0, 0);
            acc1[nt] = __builtin_amdgcn_mfma_f32_16x16x32_bf16(al1, bh, acc1[nt], 0, 0, 0);
        }
    }

    float bias[8];
    #pragma unroll
    for (int nt = 0; nt < 8; ++nt) bias[nt] = brel[nt * 16 + l15];

    #pragma unroll
    for (int r = 0; r < 4; ++r) {
        // tile 0
        float ss = 0.f;
        #pragma unroll
        for (int nt = 0; nt < 8; ++nt) {
            float a = acc0[nt][r] + bias[nt];
            acc0[nt][r] = a;
            ss = fmaf(a, a, ss);
        }
        ss += __shfl_xor(ss, 1, 64);
        ss += __shfl_xor(ss, 2, 64);
        ss += __shfl_xor(ss, 4, 64);
        ss += __shfl_xor(ss, 8, 64);
        float inv = 1.0f / fmaxf(sqrtf(ss), 1e-12f);
        int row = tbase + (lane >> 4) * 4 + r;
        if (row < N) {
            float* o = inout + (size_t)row * D + l15;
            #pragma unroll
            for (int nt = 0; nt < 8; ++nt)
                o[nt * 16] = acc0[nt][r] * inv;
        }
        // tile 1
        float ss1 = 0.f;
        #pragma unroll
        for (int nt = 0; nt < 8; ++nt) {
            float a = acc1[nt][r] + bias[nt];
            acc1[nt][r] = a;
            ss1 = fmaf(a, a, ss1);
        }
        ss1 += __shfl_xor(ss1, 1, 64);
        ss1 += __shfl_xor(ss1, 2, 64);
        ss1 += __shfl_xor(ss1, 4, 64);
        ss1 += __shfl_xor(ss1, 8, 64);
        float inv1 = 1.0f / fmaxf(sqrtf(ss1), 1e-12f);
        int row1 = tbase + 16 + (lane >> 4) * 4 + r;
        if (row1 < N) {
            float* o = inout + (size_t)row1 * D + l15;
            #pragma unroll
            for (int nt = 0; nt < 8; ++nt)
                o[nt * 16] = acc1[nt][r] * inv1;
        }
    }
}

extern "C" void kernel_launch(void* const* d_in, const int* in_sizes, int n_in,
                              void* d_out, int out_size, void* d_ws, size_t ws_size,
                              hipStream_t stream)
{
    const float* x    = (const float*)d_in[0];
    const int*   ei   = (const int*)d_in[2];
    const float* Wrel = (const float*)d_in[3];
    const float* brel = (const float*)d_in[4];
    const float* Wroot= (const float*)d_in[5];
    int N = in_sizes[0] / D;
    int E = in_sizes[2] / 2;
    float* out = (float*)d_out;

    unsigned short* Whi = (unsigned short*)d_ws;
    unsigned short* Wlo = Whi + 32768;
    unsigned short* xbf = Wlo + 32768;                 // N*D bf16

    sage_wprep<<<128, 256, 0, stream>>>(Wrel, Wroot, Whi, Wlo);

    int nbuck = (N + (1 << BSH) - 1) >> BSH;
    int* gbh     = (int*)(xbf + (size_t)N * D);
    int* boff    = gbh + NBMAX;
    int* gcur    = boff + NBMAX;
    int* row_ptr = gcur + NBMAX;
    unsigned* bucketed = (unsigned*)(row_ptr + N + 1);
    int* perm    = (int*)(bucketed + E);
    size_t need  = (size_t)((char*)(perm + E) - (char*)d_ws);

    if (N <= (1 << 17) && nbuck <= NBMAX && need <= ws_size) {
        long long total8 = (long long)N * D / 8;
        sage_xprep<<<(int)((total8 + 255) / 256), 256, 0, stream>>>(x, xbf, total8);
        hipMemsetAsync(gbh, 0, NBMAX * sizeof(int), stream);
        bucket_hist<<<256, 256, 0, stream>>>(ei + E, gbh, E, nbuck);
        bucket_scan<<<1, NBMAX, 0, stream>>>(gbh, boff, gcur, nbuck);
        bucketize<<<(E + PASSA_TILE - 1) / PASSA_TILE, 256, 0, stream>>>(
            ei, gcur, bucketed, E, nbuck);
        bucket_csr<<<nbuck, 256, 0, stream>>>(
            bucketed, gbh, boff, row_ptr, perm, N, E);
        sage_gather_bf<<<(N + 3) / 4, 256, 0, stream>>>(xbf, row_ptr, perm, out, N);
    } else {
        // emergency path
        int* hist    = (int*)(Wlo + 32768);
        int* rp      = hist + N;
        int* cursor  = rp + N + 1;
        int* perm2   = cursor + N;
        hipMemsetAsync(hist, 0, (size_t)N * sizeof(int), stream);
        int eblocks = (E + 255) / 256;
        sage_hist_old<<<eblocks, 256, 0, stream>>>(ei, hist, E);
        sage_scan_old<<<1, 1024, 0, stream>>>(hist, rp, cursor, N);
        sage_fill_old<<<eblocks, 256, 0, stream>>>(ei, cursor, perm2, E);
        sage_gather<<<(N + 3) / 4, 256, 0, stream>>>(x, rp, perm2, out, N);
    }

    sage_transform_mfma<<<(N + 127) / 128, 256, 0, stream>>>(
        out, x, Whi, Wlo, brel, N);
}